// Round 1
// baseline (1185.987 us; speedup 1.0000x reference)
//
#include <hip/hip_runtime.h>
#include <hip/hip_bf16.h>
#include <cstddef>

#define C_CH   384
#define HW     56
#define PLANE  (HW*HW)          // 3136
#define KK     31
#define PAD    15
#define LROWS  86               // 56 + 30
#define LSTRIDE 88              // padded row stride (floats)
#define WSTRIDE 32              // padded weight row stride (floats)
#define TPB    448              // 7 waves

// ---------------- weight merge + BN fold ----------------
// merged[c][ky][kx] = lk_w*s1 + center-embedded sk_w*s2 ; bias[c] = b1 + b2
__global__ void prep_weights(const float* __restrict__ lk_w,
                             const float* __restrict__ lk_g, const float* __restrict__ lk_b,
                             const float* __restrict__ lk_m, const float* __restrict__ lk_v,
                             const float* __restrict__ sk_w,
                             const float* __restrict__ sk_g, const float* __restrict__ sk_b,
                             const float* __restrict__ sk_m, const float* __restrict__ sk_v,
                             float* __restrict__ wm, float* __restrict__ bias) {
    const int c = blockIdx.x;
    const float s1 = lk_g[c] / sqrtf(lk_v[c] + 1e-5f);
    const float s2 = sk_g[c] / sqrtf(sk_v[c] + 1e-5f);
    if (threadIdx.x == 0)
        bias[c] = (lk_b[c] - lk_m[c] * s1) + (sk_b[c] - sk_m[c] * s2);
    for (int i = threadIdx.x; i < KK * WSTRIDE; i += blockDim.x) {
        const int ky = i >> 5, kx = i & 31;
        float w = 0.f;
        if (kx < KK) {
            w = lk_w[c * (KK*KK) + ky * KK + kx] * s1;
            if (ky >= 13 && ky <= 17 && kx >= 13 && kx <= 17)
                w += sk_w[c * 25 + (ky - 13) * 5 + (kx - 13)] * s2;
        }
        wm[c * (KK*WSTRIDE) + i] = w;
    }
}

// ---------------- merged 31x31 depthwise conv ----------------
__global__ __launch_bounds__(TPB) void dwconv31(const float* __restrict__ x,
                                                const float* __restrict__ wm,
                                                const float* __restrict__ bias,
                                                float* __restrict__ out) {
    __shared__ float lds[LROWS * LSTRIDE];   // 86*88*4 = 30.3 KB

    const int plane = blockIdx.x;            // n*384 + c
    const int c = plane % C_CH;
    const float* __restrict__ xp = x + (size_t)plane * PLANE;

    // stage zero-padded plane: lds row r holds global row r-15
    for (int i = threadIdx.x; i < LROWS * LROWS; i += TPB) {
        const int r = i / LROWS;
        const int col = i - r * LROWS;
        const int gr = r - PAD, gc = col - PAD;
        float v = 0.f;
        if ((unsigned)gr < (unsigned)HW && (unsigned)gc < (unsigned)HW)
            v = xp[gr * HW + gc];
        lds[r * LSTRIDE + col] = v;
    }
    __syncthreads();

    const int tx = threadIdx.x % 7;          // 7 x-tiles of 8 outputs
    const int ty = threadIdx.x / 7;          // 0..63, rows >=56 idle
    if (ty >= HW) return;

    const int x0 = tx * 8;                   // 16B-aligned LDS window base
    const float* __restrict__ wr = wm + c * (KK*WSTRIDE);

    float acc[8];
    #pragma unroll
    for (int i = 0; i < 8; ++i) acc[i] = 0.f;

    for (int ky = 0; ky < KK; ++ky) {
        // 40-float row window (need 38), 16B-aligned -> ds_read_b128 x10
        float rbuf[40];
        const float* lp = &lds[(ty + ky) * LSTRIDE + x0];
        #pragma unroll
        for (int u = 0; u < 40; u += 4) {
            rbuf[u + 0] = lp[u + 0];
            rbuf[u + 1] = lp[u + 1];
            rbuf[u + 2] = lp[u + 2];
            rbuf[u + 3] = lp[u + 3];
        }
        #pragma unroll
        for (int kx = 0; kx < KK; ++kx) {
            const float w = wr[ky * WSTRIDE + kx];   // block-uniform -> s_load
            #pragma unroll
            for (int i = 0; i < 8; ++i)
                acc[i] = fmaf(rbuf[kx + i], w, acc[i]);
        }
    }

    const float b = bias[c];
    float4 o0 = { acc[0] + b, acc[1] + b, acc[2] + b, acc[3] + b };
    float4 o1 = { acc[4] + b, acc[5] + b, acc[6] + b, acc[7] + b };
    float4* op = (float4*)(out + (size_t)plane * PLANE + ty * HW + x0);
    op[0] = o0;
    op[1] = o1;
}

extern "C" void kernel_launch(void* const* d_in, const int* in_sizes, int n_in,
                              void* d_out, int out_size, void* d_ws, size_t ws_size,
                              hipStream_t stream) {
    const float* x    = (const float*)d_in[0];
    const float* lk_w = (const float*)d_in[1];
    const float* lk_g = (const float*)d_in[2];
    const float* lk_b = (const float*)d_in[3];
    const float* lk_m = (const float*)d_in[4];
    const float* lk_v = (const float*)d_in[5];
    const float* sk_w = (const float*)d_in[6];
    const float* sk_g = (const float*)d_in[7];
    const float* sk_b = (const float*)d_in[8];
    const float* sk_m = (const float*)d_in[9];
    const float* sk_v = (const float*)d_in[10];
    float* out = (float*)d_out;

    float* wm   = (float*)d_ws;                       // 384*31*32 floats
    float* bias = wm + C_CH * (KK * WSTRIDE);         // 384 floats

    prep_weights<<<C_CH, 256, 0, stream>>>(lk_w, lk_g, lk_b, lk_m, lk_v,
                                           sk_w, sk_g, sk_b, sk_m, sk_v,
                                           wm, bias);

    const int nplanes = 16 * C_CH;                    // 6144
    dwconv31<<<nplanes, TPB, 0, stream>>>(x, wm, bias, out);
}

// Round 2
// 507.845 us; speedup vs baseline: 2.3353x; 2.3353x over previous
//
#include <hip/hip_runtime.h>
#include <hip/hip_bf16.h>
#include <cstddef>
#include <cstdint>

typedef _Float16 half2_t __attribute__((ext_vector_type(2)));

#define C_CH   384
#define HW     56
#define PLANE  3136
#define KK     31
#define NPAIR  16            // 16 half2 weight pairs per kernel row (pair 15 = (w30, 0))
#define LROWS  86            // 56 + 2*15 halo rows
#define LSTW   52            // LDS row stride in dwords (104 halfs); 364 = 7*52 ≡ 12 mod 32 -> quad spread
#define LDS_DW (LROWS * LSTW)   // 4472 dwords = 17.9 KB

static __device__ __forceinline__ uint32_t pack_h2(float a, float b) {
    return __builtin_bit_cast(uint32_t, __builtin_amdgcn_cvt_pkrtz(a, b));
}
static __device__ __forceinline__ half2_t as_h2(uint32_t u) {
    return __builtin_bit_cast(half2_t, u);
}

// ---------------- weight merge + BN fold + f16 pair packing ----------------
__global__ void prep_weights(const float* __restrict__ lk_w,
                             const float* __restrict__ lk_g, const float* __restrict__ lk_b,
                             const float* __restrict__ lk_m, const float* __restrict__ lk_v,
                             const float* __restrict__ sk_w,
                             const float* __restrict__ sk_g, const float* __restrict__ sk_b,
                             const float* __restrict__ sk_m, const float* __restrict__ sk_v,
                             uint32_t* __restrict__ wpk, float* __restrict__ bias) {
    const int c = blockIdx.x;
    const float s1 = lk_g[c] / sqrtf(lk_v[c] + 1e-5f);
    const float s2 = sk_g[c] / sqrtf(sk_v[c] + 1e-5f);
    if (threadIdx.x == 0)
        bias[c] = (lk_b[c] - lk_m[c] * s1) + (sk_b[c] - sk_m[c] * s2);

    auto merged = [&](int ky, int kx) -> float {
        float w = lk_w[c * (KK*KK) + ky * KK + kx] * s1;
        if (ky >= 13 && ky <= 17 && kx >= 13 && kx <= 17)
            w += sk_w[c * 25 + (ky - 13) * 5 + (kx - 13)] * s2;
        return w;
    };

    for (int i = threadIdx.x; i < KK * NPAIR; i += blockDim.x) {
        const int ky = i / NPAIR, m = i - ky * NPAIR;
        const int kx0 = 2 * m;
        const float w0 = merged(ky, kx0);
        const float w1 = (kx0 + 1 < KK) ? merged(ky, kx0 + 1) : 0.f;
        wpk[c * (KK*NPAIR) + i] = pack_h2(w0, w1);
    }
}

// ---------------- merged 31x31 depthwise conv, f16 dot2, 7x8 tiles ----------------
__global__ __launch_bounds__(64) void dwconv31(const float* __restrict__ x,
                                               const uint32_t* __restrict__ wpk,
                                               const float* __restrict__ bias,
                                               float* __restrict__ out) {
    __shared__ uint32_t ldsw[LDS_DW];   // f16 plane, halo-padded; half h = global col h-16

    const int plane = blockIdx.x;       // n*384 + c
    const int c = plane % C_CH;
    const int tid = threadIdx.x;
    const float* __restrict__ xp = x + (size_t)plane * PLANE;

    // zero-fill (halo), then stage interior as packed f16
    {
        uint4 z = make_uint4(0u, 0u, 0u, 0u);
        uint4* l4 = (uint4*)ldsw;
        for (int i = tid; i < LDS_DW / 4; i += 64) l4[i] = z;
    }
    __syncthreads();
    {
        const float4* xp4 = (const float4*)xp;
        for (int i = tid; i < (HW * HW) / 4; i += 64) {   // 784 float4
            const int r = i / 14, q = i - r * 14;          // row r, cols 4q..4q+3
            float4 v = xp4[i];
            uint2 h;
            h.x = pack_h2(v.x, v.y);
            h.y = pack_h2(v.z, v.w);
            *(uint2*)&ldsw[(15 + r) * LSTW + 8 + 2 * q] = h;
        }
    }
    __syncthreads();

    if (tid >= 56) return;
    const int rt = tid / 7;             // 8 row-tiles of 7
    const int tx = tid - rt * 7;        // 7 col-tiles of 8
    const int r0 = rt * 7;
    const uint32_t* __restrict__ wc = wpk + c * (KK * NPAIR);

    float acc[7][8];
    #pragma unroll
    for (int j = 0; j < 7; ++j)
        #pragma unroll
        for (int i = 0; i < 8; ++i) acc[j][i] = 0.f;

    // input rows r0 .. r0+36; window halfs cover global cols 8tx-16 .. 8tx+23
    #pragma unroll 1
    for (int iy = 0; iy < 37; ++iy) {
        uint32_t re[20];
        {
            const uint4* lp = (const uint4*)&ldsw[(r0 + iy) * LSTW + 4 * tx];
            #pragma unroll
            for (int u = 0; u < 5; ++u) {
                uint4 t = lp[u];
                re[4*u + 0] = t.x; re[4*u + 1] = t.y;
                re[4*u + 2] = t.z; re[4*u + 3] = t.w;
            }
        }
        uint32_t ro[19];
        #pragma unroll
        for (int j2 = 0; j2 < 19; ++j2)
            ro[j2] = (re[j2] >> 16) | (re[j2 + 1] << 16);   // elements (2j+1, 2j+2)

        const int jlo = (iy - 30 < 0) ? 0 : iy - 30;
        const int jhi = (iy < 6) ? iy : 6;

        #pragma unroll
        for (int j = 0; j < 7; ++j) {
            if (j < jlo || j > jhi) continue;               // uniform branch
            const uint32_t* __restrict__ wrow = wc + (iy - j) * NPAIR;
            #pragma unroll
            for (int m = 0; m < NPAIR; ++m) {
                const half2_t w2 = as_h2(wrow[m]);
                // out col i, tap pair kx=(2m,2m+1) -> window elems (i+2m+1, i+2m+2)
                acc[j][0] = __builtin_amdgcn_fdot2(as_h2(ro[m    ]), w2, acc[j][0], false);
                acc[j][1] = __builtin_amdgcn_fdot2(as_h2(re[1 + m]), w2, acc[j][1], false);
                acc[j][2] = __builtin_amdgcn_fdot2(as_h2(ro[1 + m]), w2, acc[j][2], false);
                acc[j][3] = __builtin_amdgcn_fdot2(as_h2(re[2 + m]), w2, acc[j][3], false);
                acc[j][4] = __builtin_amdgcn_fdot2(as_h2(ro[2 + m]), w2, acc[j][4], false);
                acc[j][5] = __builtin_amdgcn_fdot2(as_h2(re[3 + m]), w2, acc[j][5], false);
                acc[j][6] = __builtin_amdgcn_fdot2(as_h2(ro[3 + m]), w2, acc[j][6], false);
                acc[j][7] = __builtin_amdgcn_fdot2(as_h2(re[4 + m]), w2, acc[j][7], false);
            }
        }
    }

    const float b = bias[c];
    float* __restrict__ op = out + (size_t)plane * PLANE;
    #pragma unroll
    for (int j = 0; j < 7; ++j) {
        float4 o0 = { acc[j][0] + b, acc[j][1] + b, acc[j][2] + b, acc[j][3] + b };
        float4 o1 = { acc[j][4] + b, acc[j][5] + b, acc[j][6] + b, acc[j][7] + b };
        float4* dst = (float4*)&op[(r0 + j) * HW + 8 * tx];
        dst[0] = o0;
        dst[1] = o1;
    }
}

extern "C" void kernel_launch(void* const* d_in, const int* in_sizes, int n_in,
                              void* d_out, int out_size, void* d_ws, size_t ws_size,
                              hipStream_t stream) {
    const float* x    = (const float*)d_in[0];
    const float* lk_w = (const float*)d_in[1];
    const float* lk_g = (const float*)d_in[2];
    const float* lk_b = (const float*)d_in[3];
    const float* lk_m = (const float*)d_in[4];
    const float* lk_v = (const float*)d_in[5];
    const float* sk_w = (const float*)d_in[6];
    const float* sk_g = (const float*)d_in[7];
    const float* sk_b = (const float*)d_in[8];
    const float* sk_m = (const float*)d_in[9];
    const float* sk_v = (const float*)d_in[10];
    float* out = (float*)d_out;

    uint32_t* wpk = (uint32_t*)d_ws;                  // 384*31*16 dwords = 762 KB
    float* bias   = (float*)(wpk + C_CH * KK * NPAIR);

    prep_weights<<<C_CH, 64, 0, stream>>>(lk_w, lk_g, lk_b, lk_m, lk_v,
                                          sk_w, sk_g, sk_b, sk_m, sk_v,
                                          wpk, bias);

    dwconv31<<<16 * C_CH, 64, 0, stream>>>(x, wpk, bias, out);
}